// Round 10
// baseline (287.663 us; speedup 1.0000x reference)
//
#include <hip/hip_runtime.h>
#include <hip/hip_bf16.h>
#include <hip/hip_cooperative_groups.h>

namespace cg = cooperative_groups;

// ProbSparse attention (Informer). B=4, L=2048, H=8, D=64, S=TOP=40.
constexpr int B = 4, L = 2048, H = 8, D = 64, S = 40, TOP = 40;
constexpr int NMT = B * H * L / 4;     // 16384 M tasks (4 rows each) for mega P1
constexpr int NMB = B * H * L / 8;     // fallback kA grid
constexpr int CCM = 64, NCCM = L / CCM; // mega split-K: 64-key chunks, 32 per bh

typedef float f32x4 __attribute__((ext_vector_type(4)));

// ===================== MEGA (cooperative, tier-1): all phases in one kernel ==============
// P1: sparsity measure M + V-mean partials   (16384 + 512 tasks, XCD-pinned)
// P2: top-40 per bh (32 tasks) + mean-broadcast fill of out (2048 tasks)
// P3: split-K selected attention, CC=64      (1024 tasks)
// P4: combine partials + scatter             (320 tasks)

__device__ __forceinline__ void bodyM(int task, int t, const float* __restrict__ Q,
                                      const float* __restrict__ K, const int* __restrict__ idx,
                                      float* __restrict__ M) {
    int xcd = task & 7, slot = task >> 3;           // [0,2048)
    int bh = xcd * 4 + (slot & 3);
    int lb = slot >> 2;                             // [0,512)
    int lane = t & 63;
    int sq = lane >> 4, dq = lane & 15;
    int b = bh >> 3, h = bh & 7;
    int l = lb * 4 + (t >> 6);
    const float4 q4 = *(const float4*)&Q[(((b * L + l) * H + h) << 6) + dq * 4];
    int myidx = (lane < S) ? idx[l * S + lane] : 0;
    int ki[10];
    #pragma unroll
    for (int i = 0; i < 10; ++i) ki[i] = __shfl(myidx, i * 4 + sq, 64);
    float4 kv[10];
    #pragma unroll
    for (int i = 0; i < 10; ++i)
        kv[i] = *(const float4*)&K[(((b * L + ki[i]) * H + h) << 6) + dq * 4];
    float maxv = -3.4e38f, sumv = 0.f;
    #pragma unroll
    for (int i = 0; i < 10; ++i) {
        float p = q4.x * kv[i].x + q4.y * kv[i].y + q4.z * kv[i].z + q4.w * kv[i].w;
        p += __shfl_xor(p, 1); p += __shfl_xor(p, 2);
        p += __shfl_xor(p, 4); p += __shfl_xor(p, 8);
        maxv = fmaxf(maxv, p); sumv += p;
    }
    maxv = fmaxf(maxv, __shfl_xor(maxv, 16));
    maxv = fmaxf(maxv, __shfl_xor(maxv, 32));
    sumv += __shfl_xor(sumv, 16);
    sumv += __shfl_xor(sumv, 32);
    if (lane == 0) M[bh * L + l] = maxv - sumv * (1.0f / (float)L);
}

__device__ __forceinline__ void bodyVmean(int m, int t, const float* __restrict__ V,
                                          float* __restrict__ Vpart, float* smem) {
    float4* red = (float4*)smem;
    int xcd = m & 7, slot = m >> 3;                 // [0,64)
    int bh = xcd * 4 + (slot & 3);
    int chunk = slot >> 2;                          // [0,16)
    int b = bh >> 3, h = bh & 7;
    int d4 = t & 15, rr = t >> 4;
    int l0 = chunk * 128;
    float4 acc = make_float4(0.f, 0.f, 0.f, 0.f);
    #pragma unroll
    for (int s = 0; s < 8; ++s) {
        int l = l0 + rr + s * 16;
        float4 v = *(const float4*)&V[(((b * L + l) * H + h) << 6) + d4 * 4];
        acc.x += v.x; acc.y += v.y; acc.z += v.z; acc.w += v.w;
    }
    __syncthreads();                                 // smem re-entry guard
    red[t] = acc;
    __syncthreads();
    #pragma unroll
    for (int off = 8; off > 0; off >>= 1) {
        if (rr < off) {
            float4 o = red[t + off * 16];
            red[t].x += o.x; red[t].y += o.y; red[t].z += o.z; red[t].w += o.w;
        }
        __syncthreads();
    }
    if (rr == 0) *(float4*)&Vpart[(bh * 16 + chunk) * 64 + d4 * 4] = red[t];
}

__device__ __forceinline__ void bodyTopk(int bh, int t, const float* __restrict__ M,
                                         int* __restrict__ Mtop, float* smem) {
    float* swv = smem;
    int*   swi = (int*)(smem + 4);
    int*   winS = (int*)(smem + 8);
    const int lane = t & 63, wid = t >> 6;
    float v[8];
    #pragma unroll
    for (int j = 0; j < 8; ++j) v[j] = M[bh * L + j * 256 + t];
    float bv = v[0]; int bj = 0;
    #pragma unroll
    for (int j = 1; j < 8; ++j) if (v[j] > bv) { bv = v[j]; bj = j; }
    for (int it = 0; it < TOP; ++it) {
        float cv = bv; int ci = bj * 256 + t;
        #pragma unroll
        for (int m = 1; m < 64; m <<= 1) {
            float ov = __shfl_xor(cv, m); int oi = __shfl_xor(ci, m);
            if (ov > cv || (ov == cv && oi < ci)) { cv = ov; ci = oi; }
        }
        if (lane == 0) { swv[wid] = cv; swi[wid] = ci; }
        __syncthreads();
        if (t == 0) {
            float fv = swv[0]; int fi = swi[0];
            #pragma unroll
            for (int w = 1; w < 4; ++w)
                if (swv[w] > fv || (swv[w] == fv && swi[w] < fi)) { fv = swv[w]; fi = swi[w]; }
            Mtop[bh * TOP + it] = fi;
            *winS = fi;
        }
        __syncthreads();
        const int wl = *winS;
        if ((wl & 255) == t) {
            if ((wl >> 8) == 0) v[0] = -3.4e38f;
            if ((wl >> 8) == 1) v[1] = -3.4e38f;
            if ((wl >> 8) == 2) v[2] = -3.4e38f;
            if ((wl >> 8) == 3) v[3] = -3.4e38f;
            if ((wl >> 8) == 4) v[4] = -3.4e38f;
            if ((wl >> 8) == 5) v[5] = -3.4e38f;
            if ((wl >> 8) == 6) v[6] = -3.4e38f;
            if ((wl >> 8) == 7) v[7] = -3.4e38f;
            bv = v[0]; bj = 0;
            #pragma unroll
            for (int j = 1; j < 8; ++j) if (v[j] > bv) { bv = v[j]; bj = j; }
        }
    }
}

__device__ __forceinline__ void bodyFill(int f, int t, const float* __restrict__ Vpart,
                                         float* __restrict__ out, float* smem) {
    float* smean = smem;
    int i0 = f * 512;                               // float4 index into out
    int bh = i0 >> 15;                              // 32768 float4 per bh
    __syncthreads();                                 // smem re-entry guard
    if (t < 64) {
        float s = 0.f;
        #pragma unroll
        for (int c = 0; c < 16; ++c) s += Vpart[(bh * 16 + c) * 64 + t];
        smean[t] = s * (1.0f / (float)L);
    }
    __syncthreads();
    const float4* m4 = (const float4*)smean;
    float4* o4 = (float4*)out;
    o4[i0 + t]       = m4[t & 15];
    o4[i0 + 256 + t] = m4[t & 15];
}

__device__ __forceinline__ void bodyKC(int task, int t, const float* __restrict__ Q,
                                       const float* __restrict__ K, const float* __restrict__ V,
                                       const int* __restrict__ Mtop, float* __restrict__ Npart,
                                       float* __restrict__ Zpart, float* smem) {
    constexpr int CC = CCM, NCC = NCCM;             // 64 / 32
    constexpr int KPT = 2, LDK = 66, LDP = 66, LDV = 68, VPT = 4;
    float* KV = smem;                               // [0, 4352)
    float* Qs = smem + 4352;                        // [4352, 6912)
    float* Ps = smem + 6912;                        // [6912, 9552)
    const int bh = task / NCC, kc = task % NCC;
    const int b = bh >> 3, h = bh & 7;
    const int k0 = kc * CC;
    __syncthreads();                                 // smem re-entry guard
    for (int i = t; i < CC * 16; i += 256) {
        int kk = i >> 4, d4 = i & 15;
        float4 kv = *(const float4*)&K[(((b * L + k0 + kk) * H + h) << 6) + d4 * 4];
        KV[(d4 * 4 + 0) * LDK + kk] = kv.x;
        KV[(d4 * 4 + 1) * LDK + kk] = kv.y;
        KV[(d4 * 4 + 2) * LDK + kk] = kv.z;
        KV[(d4 * 4 + 3) * LDK + kk] = kv.w;
    }
    for (int i = t; i < TOP * 16; i += 256) {
        int u = i >> 4, d4 = i & 15;
        int lsel = Mtop[bh * TOP + u];
        *(float4*)&Qs[u * 64 + d4 * 4] =
            *(const float4*)&Q[(((b * L + lsel) * H + h) << 6) + d4 * 4];
    }
    float4 vpre[VPT];
    #pragma unroll
    for (int p = 0; p < VPT; ++p) {
        int i = p * 256 + t;
        int kk = i >> 4, d4 = i & 15;
        vpre[p] = *(const float4*)&V[(((b * L + k0 + kk) * H + h) << 6) + d4 * 4];
    }
    __syncthreads();
    const int k2 = t & 31, ug = t >> 5;
    float acc[5][KPT];
    #pragma unroll
    for (int j = 0; j < 5; ++j)
        #pragma unroll
        for (int p = 0; p < KPT; ++p) acc[j][p] = 0.f;
    #pragma unroll 4
    for (int d4 = 0; d4 < 16; ++d4) {
        float kr[4][KPT];
        #pragma unroll
        for (int rr = 0; rr < 4; ++rr)
            #pragma unroll
            for (int p = 0; p < KPT; ++p)
                kr[rr][p] = KV[(d4 * 4 + rr) * LDK + k2 * KPT + p];
        #pragma unroll
        for (int j = 0; j < 5; ++j) {
            float4 q4 = *(const float4*)&Qs[(ug * 5 + j) * 64 + d4 * 4];
            #pragma unroll
            for (int p = 0; p < KPT; ++p)
                acc[j][p] += q4.x * kr[0][p] + q4.y * kr[1][p] + q4.z * kr[2][p] + q4.w * kr[3][p];
        }
    }
    #pragma unroll
    for (int j = 0; j < 5; ++j) {
        int u = ug * 5 + j;
        float z = 0.f;
        #pragma unroll
        for (int p = 0; p < KPT; ++p) {
            float e = __expf(acc[j][p] * 0.125f - 16.0f);
            Ps[u * LDP + k2 * KPT + p] = e;
            z += e;
        }
        z += __shfl_xor(z, 1); z += __shfl_xor(z, 2); z += __shfl_xor(z, 4);
        z += __shfl_xor(z, 8); z += __shfl_xor(z, 16);
        if (k2 == 0) Zpart[(bh * TOP + u) * NCC + kc] = z;
    }
    __syncthreads();
    #pragma unroll
    for (int p = 0; p < VPT; ++p) {
        int i = p * 256 + t;
        int kk = i >> 4, d4 = i & 15;
        *(float4*)&KV[kk * LDV + d4 * 4] = vpre[p];
    }
    __syncthreads();
    const int d4v = t & 15, ug2 = t >> 4;
    float4 o0 = make_float4(0,0,0,0), o1 = make_float4(0,0,0,0), o2 = make_float4(0,0,0,0);
    #pragma unroll 4
    for (int kk = 0; kk < CC; ++kk) {
        float4 vv = *(const float4*)&KV[kk * LDV + d4v * 4];
        float e0 = Ps[ug2 * LDP + kk];
        float e1 = Ps[(ug2 + 16) * LDP + kk];
        o0.x += e0 * vv.x; o0.y += e0 * vv.y; o0.z += e0 * vv.z; o0.w += e0 * vv.w;
        o1.x += e1 * vv.x; o1.y += e1 * vv.y; o1.z += e1 * vv.z; o1.w += e1 * vv.w;
        if (ug2 < 8) {
            float e2 = Ps[(ug2 + 32) * LDP + kk];
            o2.x += e2 * vv.x; o2.y += e2 * vv.y; o2.z += e2 * vv.z; o2.w += e2 * vv.w;
        }
    }
    *(float4*)&Npart[((bh * TOP + ug2) * NCC + kc) * 64 + d4v * 4] = o0;
    *(float4*)&Npart[((bh * TOP + ug2 + 16) * NCC + kc) * 64 + d4v * 4] = o1;
    if (ug2 < 8)
        *(float4*)&Npart[((bh * TOP + ug2 + 32) * NCC + kc) * 64 + d4v * 4] = o2;
}

__device__ __forceinline__ void bodyKD(int task, int t, const int* __restrict__ Mtop,
                                       const float* __restrict__ Npart, const float* __restrict__ Zpart,
                                       float* __restrict__ out) {
    const int g = task * 4 + (t >> 6);              // (bh,u) flat in [0,1280)
    const int d = t & 63;
    const int bh = g / TOP;
    const int lsel = Mtop[g];
    float z = 0.f;
    #pragma unroll
    for (int c = 0; c < NCCM; ++c) z += Zpart[g * NCCM + c];
    float n = 0.f;
    #pragma unroll
    for (int c = 0; c < NCCM; ++c) n += Npart[(g * NCCM + c) * 64 + d];
    out[((bh * L + lsel) << 6) + d] = n / z;
}

__global__ __launch_bounds__(256, 4) void mega(const float* __restrict__ Q, const float* __restrict__ K,
                                               const float* __restrict__ V, const int* __restrict__ idx,
                                               float* __restrict__ out, float* __restrict__ M,
                                               int* __restrict__ Mtop, float* __restrict__ Vpart,
                                               float* __restrict__ Npart, float* __restrict__ Zpart) {
    __shared__ __align__(16) float smem[9552];       // 38.2 KB union -> 4 blocks/CU
    cg::grid_group grid = cg::this_grid();
    const int t = threadIdx.x;
    const int nb = gridDim.x;
    // P1: M (16384 tasks) + vmean partials (512 tasks)
    for (int task = blockIdx.x; task < NMT + 512; task += nb) {
        if (task < NMT) bodyM(task, t, Q, K, idx, M);
        else            bodyVmean(task - NMT, t, V, Vpart, smem);
    }
    grid.sync();
    // P2: topk (32) + mean-broadcast fill (2048)
    for (int task = blockIdx.x; task < 32 + 2048; task += nb) {
        if (task < 32) bodyTopk(task, t, M, Mtop, smem);
        else           bodyFill(task - 32, t, Vpart, out, smem);
    }
    grid.sync();
    // P3: split-K selected attention (1024)
    for (int task = blockIdx.x; task < B * H * NCCM; task += nb)
        bodyKC(task, t, Q, K, V, Mtop, Npart, Zpart, smem);
    grid.sync();
    // P4: combine + scatter (320)
    for (int task = blockIdx.x; task < 320; task += nb)
        bodyKD(task, t, Mtop, Npart, Zpart, out);
}

// ===================== Fallback multi-kernel path (small ws / no coop) ====================

__global__ __launch_bounds__(256, 3) void kA(const float* __restrict__ Q, const float* __restrict__ K,
                                             const float* __restrict__ V, const int* __restrict__ idx,
                                             float* __restrict__ M, float* __restrict__ Vpart) {
    __shared__ float4 red[256];
    const int t = threadIdx.x;
    if (blockIdx.x < NMB) {
        int n = blockIdx.x;
        int xcd = n & 7, slot = n >> 3;
        int bh = xcd * 4 + (slot & 3);
        int lb = slot >> 2;
        int lane = t & 63, wid = t >> 6;
        int sq = lane >> 4, dq = lane & 15;
        int b = bh >> 3, h = bh & 7;
        int l0 = lb * 8 + wid * 2, l1 = l0 + 1;
        const float4 qa = *(const float4*)&Q[(((b * L + l0) * H + h) << 6) + dq * 4];
        const float4 qb = *(const float4*)&Q[(((b * L + l1) * H + h) << 6) + dq * 4];
        int ia = (lane < S) ? idx[l0 * S + lane] : 0;
        int ib = (lane < S) ? idx[l1 * S + lane] : 0;
        float mva = -3.4e38f, sva = 0.f, mvb = -3.4e38f, svb = 0.f;
        #pragma unroll
        for (int i = 0; i < 10; ++i) {
            int kia = __shfl(ia, i * 4 + sq, 64);
            float4 kv = *(const float4*)&K[(((b * L + kia) * H + h) << 6) + dq * 4];
            float p = qa.x * kv.x + qa.y * kv.y + qa.z * kv.z + qa.w * kv.w;
            p += __shfl_xor(p, 1); p += __shfl_xor(p, 2);
            p += __shfl_xor(p, 4); p += __shfl_xor(p, 8);
            mva = fmaxf(mva, p); sva += p;
        }
        #pragma unroll
        for (int i = 0; i < 10; ++i) {
            int kib = __shfl(ib, i * 4 + sq, 64);
            float4 kv = *(const float4*)&K[(((b * L + kib) * H + h) << 6) + dq * 4];
            float p = qb.x * kv.x + qb.y * kv.y + qb.z * kv.z + qb.w * kv.w;
            p += __shfl_xor(p, 1); p += __shfl_xor(p, 2);
            p += __shfl_xor(p, 4); p += __shfl_xor(p, 8);
            mvb = fmaxf(mvb, p); svb += p;
        }
        mva = fmaxf(mva, __shfl_xor(mva, 16)); mva = fmaxf(mva, __shfl_xor(mva, 32));
        sva += __shfl_xor(sva, 16); sva += __shfl_xor(sva, 32);
        mvb = fmaxf(mvb, __shfl_xor(mvb, 16)); mvb = fmaxf(mvb, __shfl_xor(mvb, 32));
        svb += __shfl_xor(svb, 16); svb += __shfl_xor(svb, 32);
        if (lane == 0) {
            M[bh * L + l0] = mva - sva * (1.0f / (float)L);
            M[bh * L + l1] = mvb - svb * (1.0f / (float)L);
        }
    } else {
        int m = blockIdx.x - NMB;
        int xcd = m & 7, slot = m >> 3;
        int bh = xcd * 4 + (slot & 3);
        int chunk = slot >> 2;
        int b = bh >> 3, h = bh & 7;
        int d4 = t & 15, rr = t >> 4;
        int l0 = chunk * 128;
        float4 acc = make_float4(0.f, 0.f, 0.f, 0.f);
        #pragma unroll
        for (int s = 0; s < 8; ++s) {
            int l = l0 + rr + s * 16;
            float4 v = *(const float4*)&V[(((b * L + l) * H + h) << 6) + d4 * 4];
            acc.x += v.x; acc.y += v.y; acc.z += v.z; acc.w += v.w;
        }
        red[t] = acc;
        __syncthreads();
        #pragma unroll
        for (int off = 8; off > 0; off >>= 1) {
            if (rr < off) {
                float4 o = red[t + off * 16];
                red[t].x += o.x; red[t].y += o.y; red[t].z += o.z; red[t].w += o.w;
            }
            __syncthreads();
        }
        if (rr == 0) *(float4*)&Vpart[(bh * 16 + chunk) * 64 + d4 * 4] = red[t];
    }
}

__global__ __launch_bounds__(256) void kB(const float* __restrict__ M, const float* __restrict__ Vpart,
                                          int* __restrict__ Mtop, float* __restrict__ mean) {
    const int t = threadIdx.x;
    __shared__ float smem[16];
    if (blockIdx.x < 32) {
        bodyTopk(blockIdx.x, t, M, Mtop, smem);
    } else {
        int bh = (blockIdx.x - 32) * 4 + (t >> 6);
        int d = t & 63;
        float s = 0.f;
        #pragma unroll
        for (int c = 0; c < 16; ++c) s += Vpart[(bh * 16 + c) * 64 + d];
        mean[bh * 64 + d] = s * (1.0f / (float)L);
    }
}

template <int CC>
__global__ __launch_bounds__(256, 4) void kC(const float* __restrict__ Q, const float* __restrict__ K,
                                             const float* __restrict__ V, const int* __restrict__ Mtop,
                                             const float* __restrict__ mean, float* __restrict__ Npart,
                                             float* __restrict__ Zpart, float* __restrict__ out) {
    constexpr int NCC = L / CC;
    constexpr int KPT = CC / 32;
    constexpr int LDK = CC + (KPT == 4 ? 4 : 2);
    constexpr int LDP = LDK;
    constexpr int LDV = 68;
    constexpr int KVSZ = (CC * LDV > 64 * LDK) ? CC * LDV : 64 * LDK;
    constexpr int VPT = CC * 16 / 256;
    __shared__ float KV[KVSZ];
    __shared__ float Qs[TOP * 64];
    __shared__ float Ps[TOP * LDP];
    const int t = threadIdx.x;
    const int nsel = B * H * NCC;
    if (blockIdx.x >= nsel) {
        const int N4 = B * H * L * D / 4;
        const float4* m4 = (const float4*)mean;
        float4* o4 = (float4*)out;
        for (int i = (blockIdx.x - nsel) * 256 + t; i < N4; i += 2048 * 256) {
            int bh = i >> 15, d4 = i & 15;
            o4[i] = m4[bh * 16 + d4];
        }
        return;
    }
    const int bh = blockIdx.x / NCC, kc = blockIdx.x % NCC;
    const int b = bh >> 3, h = bh & 7;
    const int k0 = kc * CC;
    for (int i = t; i < CC * 16; i += 256) {
        int kk = i >> 4, d4 = i & 15;
        float4 kv = *(const float4*)&K[(((b * L + k0 + kk) * H + h) << 6) + d4 * 4];
        KV[(d4 * 4 + 0) * LDK + kk] = kv.x;
        KV[(d4 * 4 + 1) * LDK + kk] = kv.y;
        KV[(d4 * 4 + 2) * LDK + kk] = kv.z;
        KV[(d4 * 4 + 3) * LDK + kk] = kv.w;
    }
    for (int i = t; i < TOP * 16; i += 256) {
        int u = i >> 4, d4 = i & 15;
        int lsel = Mtop[bh * TOP + u];
        *(float4*)&Qs[u * 64 + d4 * 4] =
            *(const float4*)&Q[(((b * L + lsel) * H + h) << 6) + d4 * 4];
    }
    float4 vpre[VPT];
    #pragma unroll
    for (int p = 0; p < VPT; ++p) {
        int i = p * 256 + t;
        int kk = i >> 4, d4 = i & 15;
        vpre[p] = *(const float4*)&V[(((b * L + k0 + kk) * H + h) << 6) + d4 * 4];
    }
    __syncthreads();
    const int k2 = t & 31, ug = t >> 5;
    float acc[5][KPT];
    #pragma unroll
    for (int j = 0; j < 5; ++j)
        #pragma unroll
        for (int p = 0; p < KPT; ++p) acc[j][p] = 0.f;
    #pragma unroll 4
    for (int d4 = 0; d4 < 16; ++d4) {
        float kr[4][KPT];
        #pragma unroll
        for (int rr = 0; rr < 4; ++rr)
            #pragma unroll
            for (int p = 0; p < KPT; ++p)
                kr[rr][p] = KV[(d4 * 4 + rr) * LDK + k2 * KPT + p];
        #pragma unroll
        for (int j = 0; j < 5; ++j) {
            float4 q4 = *(const float4*)&Qs[(ug * 5 + j) * 64 + d4 * 4];
            #pragma unroll
            for (int p = 0; p < KPT; ++p)
                acc[j][p] += q4.x * kr[0][p] + q4.y * kr[1][p] + q4.z * kr[2][p] + q4.w * kr[3][p];
        }
    }
    #pragma unroll
    for (int j = 0; j < 5; ++j) {
        int u = ug * 5 + j;
        float z = 0.f;
        #pragma unroll
        for (int p = 0; p < KPT; ++p) {
            float e = __expf(acc[j][p] * 0.125f - 16.0f);
            Ps[u * LDP + k2 * KPT + p] = e;
            z += e;
        }
        z += __shfl_xor(z, 1); z += __shfl_xor(z, 2); z += __shfl_xor(z, 4);
        z += __shfl_xor(z, 8); z += __shfl_xor(z, 16);
        if (k2 == 0) Zpart[(bh * TOP + u) * NCC + kc] = z;
    }
    __syncthreads();
    #pragma unroll
    for (int p = 0; p < VPT; ++p) {
        int i = p * 256 + t;
        int kk = i >> 4, d4 = i & 15;
        *(float4*)&KV[kk * LDV + d4 * 4] = vpre[p];
    }
    __syncthreads();
    const int d4v = t & 15, ug2 = t >> 4;
    float4 o0 = make_float4(0,0,0,0), o1 = make_float4(0,0,0,0), o2 = make_float4(0,0,0,0);
    #pragma unroll 4
    for (int kk = 0; kk < CC; ++kk) {
        float4 vv = *(const float4*)&KV[kk * LDV + d4v * 4];
        float e0 = Ps[ug2 * LDP + kk];
        float e1 = Ps[(ug2 + 16) * LDP + kk];
        o0.x += e0 * vv.x; o0.y += e0 * vv.y; o0.z += e0 * vv.z; o0.w += e0 * vv.w;
        o1.x += e1 * vv.x; o1.y += e1 * vv.y; o1.z += e1 * vv.z; o1.w += e1 * vv.w;
        if (ug2 < 8) {
            float e2 = Ps[(ug2 + 32) * LDP + kk];
            o2.x += e2 * vv.x; o2.y += e2 * vv.y; o2.z += e2 * vv.z; o2.w += e2 * vv.w;
        }
    }
    *(float4*)&Npart[((bh * TOP + ug2) * NCC + kc) * 64 + d4v * 4] = o0;
    *(float4*)&Npart[((bh * TOP + ug2 + 16) * NCC + kc) * 64 + d4v * 4] = o1;
    if (ug2 < 8)
        *(float4*)&Npart[((bh * TOP + ug2 + 32) * NCC + kc) * 64 + d4v * 4] = o2;
}

template <int NCC>
__global__ __launch_bounds__(256) void kD(const int* __restrict__ Mtop, const float* __restrict__ Npart,
                                          const float* __restrict__ Zpart, float* __restrict__ out) {
    const int t = threadIdx.x;
    const int g = blockIdx.x * 4 + (t >> 6);
    const int d = t & 63;
    const int bh = g / TOP;
    const int lsel = Mtop[g];
    float z = 0.f;
    #pragma unroll
    for (int c = 0; c < NCC; ++c) z += Zpart[g * NCC + c];
    float n = 0.f;
    #pragma unroll
    for (int c = 0; c < NCC; ++c) n += Npart[(g * NCC + c) * 64 + d];
    out[((bh * L + lsel) << 6) + d] = n / z;
}

__global__ void fill_ctx(const float* __restrict__ mean, float4* __restrict__ out) {
    const int N4 = B * H * L * D / 4;
    for (int i = blockIdx.x * 256 + threadIdx.x; i < N4; i += gridDim.x * 256) {
        int bh = i >> 15, d4 = i & 15;
        out[i] = ((const float4*)mean)[bh * 16 + d4];
    }
}
__global__ void sel_attn(const float* __restrict__ Q, const float* __restrict__ K,
                         const float* __restrict__ V, const int* __restrict__ Mtop,
                         float* __restrict__ out) {
    __shared__ float qs[D];
    __shared__ float p[L];
    __shared__ float red[256];
    int blk = blockIdx.x;
    int bh = blk / TOP, u = blk - bh * TOP;
    int b = bh >> 3, h = bh & 7;
    int t = threadIdx.x;
    int lsel = Mtop[bh * TOP + u];
    if (t < 64) qs[t] = Q[(((b * L + lsel) * H + h) << 6) + t];
    __syncthreads();
    float lsum = 0.f;
    for (int kk = 0; kk < 8; ++kk) {
        int k = kk * 256 + t;
        const float4* krow = (const float4*)&K[((b * L + k) * H + h) << 6];
        const float4* q4 = (const float4*)qs;
        float acc = 0.f;
        #pragma unroll
        for (int j = 0; j < 16; ++j) {
            float4 kv = krow[j]; float4 qv = q4[j];
            acc += qv.x * kv.x + qv.y * kv.y + qv.z * kv.z + qv.w * kv.w;
        }
        float e = __expf(acc * 0.125f - 16.0f);
        p[k] = e;
        lsum += e;
    }
    red[t] = lsum; __syncthreads();
    for (int off = 128; off > 0; off >>= 1) {
        if (t < off) red[t] += red[t + off];
        __syncthreads();
    }
    float inv = 1.0f / red[0];
    __syncthreads();
    int d = t & 63, c = t >> 6;
    float acc = 0.f;
    for (int k = c * 512; k < (c + 1) * 512; ++k)
        acc += p[k] * V[(((b * L + k) * H + h) << 6) + d];
    red[t] = acc; __syncthreads();
    if (t < 128) red[t] += red[t + 128];
    __syncthreads();
    if (t < 64) out[((bh * L + lsel) << 6) + t] = (red[t] + red[t + 64]) * inv;
}

extern "C" void kernel_launch(void* const* d_in, const int* in_sizes, int n_in,
                              void* d_out, int out_size, void* d_ws, size_t ws_size,
                              hipStream_t stream) {
    const float* Q = (const float*)d_in[0];
    const float* K = (const float*)d_in[1];
    const float* V = (const float*)d_in[2];
    const int* idx = (const int*)d_in[4];
    float* out = (float*)d_out;

    // ws layout: M [0,262144) ; Zpart [0,163840) ; Npart [163840,+npb) (overlays dead M)
    // persistent: Mtop / mean / Vpart after max(Npart end, 262144)
    char* ws = (char*)d_ws;
    const size_t NPB1 = (size_t)B * H * TOP * 32 * 64 * 4;   // NCC=32: 10,485,760
    const size_t NPB2 = (size_t)B * H * TOP * 16 * 64 * 4;   // NCC=16:  5,242,880
    auto layout = [&](size_t npb, size_t& persist) {
        size_t e = 163840 + npb;
        persist = (e > 262144 ? e : 262144);
        return persist + 5120 + 8192 + 131072 + 3072;
    };
    size_t p1, p2, p3;
    size_t need1 = layout(NPB1, p1);
    size_t need2 = layout(NPB2, p2);
    size_t need3 = layout(0, p3);
    int tier = (ws_size >= need1) ? 1 : (ws_size >= need2) ? 2 : (ws_size >= need3) ? 3 : 0;
    size_t persist = (tier == 1) ? p1 : (tier == 2) ? p2 : p3;

    float* M     = (float*)ws;
    float* Zpart = (float*)ws;
    float* Npart = (float*)(ws + 163840);
    int*   Mtop  = (int*)(ws + persist);
    float* mean  = (float*)(ws + persist + 5120);
    float* Vpart = (float*)(ws + persist + 5120 + 8192);

    if (tier == 1) {
        int bpc = 0;
        hipError_t e = hipOccupancyMaxActiveBlocksPerMultiprocessor(&bpc, mega, 256, 0);
        if (e == hipSuccess && bpc >= 1) {
            int grid = bpc * 256;                    // 256 CUs on MI355X; grid % 8 == 0
            if (grid > 4096) grid = 4096;
            void* params[] = {(void*)&Q, (void*)&K, (void*)&V, (void*)&idx, (void*)&out,
                              (void*)&M, (void*)&Mtop, (void*)&Vpart, (void*)&Npart, (void*)&Zpart};
            hipLaunchCooperativeKernel(mega, dim3(grid), dim3(256), params, 0, stream);
            return;
        }
        // coop unavailable: fall through to multi-kernel tier-1 pattern via tier-2 kernels
        tier = 2;
        persist = p2;
        Mtop  = (int*)(ws + persist);
        mean  = (float*)(ws + persist + 5120);
        Vpart = (float*)(ws + persist + 5120 + 8192);
    }

    kA<<<NMB + 512, 256, 0, stream>>>(Q, K, V, idx, M, Vpart);
    kB<<<40, 256, 0, stream>>>(M, Vpart, Mtop, mean);
    if (tier == 2) {
        kC<128><<<B * H * 16 + 2048, 256, 0, stream>>>(Q, K, V, Mtop, mean, Npart, Zpart, out);
        kD<16><<<320, 256, 0, stream>>>(Mtop, Npart, Zpart, out);
    } else {
        fill_ctx<<<2048, 256, 0, stream>>>(mean, (float4*)out);
        sel_attn<<<B * H * TOP, 256, 0, stream>>>(Q, K, V, Mtop, out);
    }
}

// Round 11
// 109.422 us; speedup vs baseline: 2.6289x; 2.6289x over previous
//
#include <hip/hip_runtime.h>
#include <hip/hip_bf16.h>

// ProbSparse attention (Informer). B=4, L=2048, H=8, D=64, S=TOP=40.
constexpr int B = 4, L = 2048, H = 8, D = 64, S = 40, TOP = 40;
constexpr int NMB = B * L;           // 8192 M-blocks: one (b,l) each, all 8 heads

// ================= K_A: compute_M (blocks 0..NMB-1) + vmean partials (next 512) ==========
// (b,l)-centric gather: K[b,ki,:,:] is a contiguous 2KB block covering ALL 8 heads and the
// sample indices depend only on l -> one coalesced gather serves 8 heads. Wave w of 4 handles
// samples w*10..w*10+9; lane covers head (lane>>4) [first 256 floats] and head 4+(lane>>4).
__global__ __launch_bounds__(256, 4) void kA(const float* __restrict__ Q, const float* __restrict__ K,
                                             const float* __restrict__ V, const int* __restrict__ idx,
                                             float* __restrict__ M, float* __restrict__ Vpart) {
    __shared__ float4 red[256];
    __shared__ float wmax[4][8], wsum[4][8];
    const int t = threadIdx.x;
    if (blockIdx.x < NMB) {
        int n = blockIdx.x;
        int b = n & 3;                                   // xcd = n&7 pins b to 2 XCDs
        int l = ((n >> 2) & 1) * 1024 + (n >> 3);
        int lane = t & 63, w = t >> 6;
        const float* Qb = Q + ((size_t)(b * L + l) << 9);
        const float* Kb = K + ((size_t)(b * L) << 9);
        float4 qa = *(const float4*)(Qb + lane * 4);          // heads 0-3
        float4 qb = *(const float4*)(Qb + 256 + lane * 4);    // heads 4-7
        int ki[10];
        #pragma unroll
        for (int i = 0; i < 10; ++i) ki[i] = idx[l * S + w * 10 + i];   // wave-uniform s_loads
        float4 ka[10], kb[10];
        #pragma unroll
        for (int i = 0; i < 10; ++i) {
            const float* kr = Kb + ((size_t)ki[i] << 9);
            ka[i] = *(const float4*)(kr + lane * 4);          // coalesced 1KB per load
            kb[i] = *(const float4*)(kr + 256 + lane * 4);
        }
        float maxa = -3.4e38f, suma = 0.f, maxb = -3.4e38f, sumb = 0.f;
        #pragma unroll
        for (int i = 0; i < 10; ++i) {
            float pa = qa.x * ka[i].x + qa.y * ka[i].y + qa.z * ka[i].z + qa.w * ka[i].w;
            float pb = qb.x * kb[i].x + qb.y * kb[i].y + qb.z * kb[i].z + qb.w * kb[i].w;
            pa += __shfl_xor(pa, 1); pa += __shfl_xor(pa, 2);
            pa += __shfl_xor(pa, 4); pa += __shfl_xor(pa, 8);
            pb += __shfl_xor(pb, 1); pb += __shfl_xor(pb, 2);
            pb += __shfl_xor(pb, 4); pb += __shfl_xor(pb, 8);
            maxa = fmaxf(maxa, pa); suma += pa;
            maxb = fmaxf(maxb, pb); sumb += pb;
        }
        if ((lane & 15) == 0) {
            int g = lane >> 4;
            wmax[w][g] = maxa;     wsum[w][g] = suma;
            wmax[w][g + 4] = maxb; wsum[w][g + 4] = sumb;
        }
        __syncthreads();
        if (t < 8) {
            float mv = wmax[0][t], sv = wsum[0][t];
            #pragma unroll
            for (int ww = 1; ww < 4; ++ww) { mv = fmaxf(mv, wmax[ww][t]); sv += wsum[ww][t]; }
            M[(b * 8 + t) * L + l] = mv - sv * (1.0f / (float)L);
        }
    } else {
        // ---- V mean partials: 512 blocks ----
        int m = blockIdx.x - NMB;                       // NMB % 8 == 0
        int xcd = m & 7, slot = m >> 3;                 // slot in [0,64)
        int bh = xcd * 4 + (slot & 3);
        int chunk = slot >> 2;                          // [0,16)
        int b = bh >> 3, h = bh & 7;
        int d4 = t & 15, rr = t >> 4;
        int l0 = chunk * 128;
        float4 acc = make_float4(0.f, 0.f, 0.f, 0.f);
        #pragma unroll
        for (int s = 0; s < 8; ++s) {
            int l = l0 + rr + s * 16;
            float4 v = *(const float4*)&V[(((b * L + l) * H + h) << 6) + d4 * 4];
            acc.x += v.x; acc.y += v.y; acc.z += v.z; acc.w += v.w;
        }
        red[t] = acc;
        __syncthreads();
        #pragma unroll
        for (int off = 8; off > 0; off >>= 1) {
            if (rr < off) {
                float4 o = red[t + off * 16];
                red[t].x += o.x; red[t].y += o.y; red[t].z += o.z; red[t].w += o.w;
            }
            __syncthreads();
        }
        if (rr == 0) *(float4*)&Vpart[(bh * 16 + chunk) * 64 + d4 * 4] = red[t];
    }
}

// ================= K_B: top-40 (blocks 0..31, one per bh, 8 vals/thread in regs)
//                        + mean finalize (blocks 32..39) =============================
__global__ __launch_bounds__(256) void kB(const float* __restrict__ M, const float* __restrict__ Vpart,
                                          int* __restrict__ Mtop, float* __restrict__ mean) {
    const int t = threadIdx.x;
    if (blockIdx.x < 32) {
        const int bh = blockIdx.x;
        const int lane = t & 63, wid = t >> 6;
        float v[8];                               // 8 regs, statically indexed everywhere
        #pragma unroll
        for (int j = 0; j < 8; ++j) v[j] = M[bh * L + j * 256 + t];
        float bv = v[0]; int bj = 0;              // cached per-thread argmax
        #pragma unroll
        for (int j = 1; j < 8; ++j) if (v[j] > bv) { bv = v[j]; bj = j; }
        __shared__ float swv[4];
        __shared__ int   swi[4];
        __shared__ int   winS;
        for (int it = 0; it < TOP; ++it) {
            float cv = bv; int ci = bj * 256 + t;      // global index l = j*256 + t
            #pragma unroll
            for (int m = 1; m < 64; m <<= 1) {
                float ov = __shfl_xor(cv, m); int oi = __shfl_xor(ci, m);
                if (ov > cv || (ov == cv && oi < ci)) { cv = ov; ci = oi; }
            }
            if (lane == 0) { swv[wid] = cv; swi[wid] = ci; }
            __syncthreads();
            if (t == 0) {
                float fv = swv[0]; int fi = swi[0];
                #pragma unroll
                for (int w = 1; w < 4; ++w)
                    if (swv[w] > fv || (swv[w] == fv && swi[w] < fi)) { fv = swv[w]; fi = swi[w]; }
                Mtop[bh * TOP + it] = fi;
                winS = fi;
            }
            __syncthreads();
            const int wl = winS;
            if ((wl & 255) == t) {                 // owner thread: kill + rescan 8 (static)
                if ((wl >> 8) == 0) v[0] = -3.4e38f;
                if ((wl >> 8) == 1) v[1] = -3.4e38f;
                if ((wl >> 8) == 2) v[2] = -3.4e38f;
                if ((wl >> 8) == 3) v[3] = -3.4e38f;
                if ((wl >> 8) == 4) v[4] = -3.4e38f;
                if ((wl >> 8) == 5) v[5] = -3.4e38f;
                if ((wl >> 8) == 6) v[6] = -3.4e38f;
                if ((wl >> 8) == 7) v[7] = -3.4e38f;
                bv = v[0]; bj = 0;
                #pragma unroll
                for (int j = 1; j < 8; ++j) if (v[j] > bv) { bv = v[j]; bj = j; }
            }
        }
    } else {
        int bh = (blockIdx.x - 32) * 4 + (t >> 6);
        int d = t & 63;
        float s = 0.f;
        #pragma unroll
        for (int c = 0; c < 16; ++c) s += Vpart[(bh * 16 + c) * 64 + d];
        mean[bh * 64 + d] = s * (1.0f / (float)L);
    }
}

// ================= K_C: split-K selected attention (blocks [0, B*H*NCC)) + fill (next 2048)
// Fixed-shift softmax: e = exp(s*0.125 - 16), shift-invariant.
template <int CC>
__global__ __launch_bounds__(256, 4) void kC(const float* __restrict__ Q, const float* __restrict__ K,
                                             const float* __restrict__ V, const int* __restrict__ Mtop,
                                             const float* __restrict__ mean, float* __restrict__ Npart,
                                             float* __restrict__ Zpart, float* __restrict__ out) {
    constexpr int NCC = L / CC;
    constexpr int KPT = CC / 32;                       // keys per thread in score phase
    constexpr int LDK = CC + (KPT == 4 ? 4 : 2);       // K^T row stride
    constexpr int LDP = LDK;
    constexpr int LDV = 68;
    constexpr int KVSZ = (CC * LDV > 64 * LDK) ? CC * LDV : 64 * LDK;
    constexpr int VPT = CC * 16 / 256;                 // V float4 loads per thread (CC=64 -> 4)
    __shared__ float KV[KVSZ];
    __shared__ float Qs[TOP * 64];
    __shared__ float Ps[TOP * LDP];
    const int t = threadIdx.x;
    const int nsel = B * H * NCC;
    if (blockIdx.x >= nsel) {
        // ---- broadcast-fill context with mean ----
        const int N4 = B * H * L * D / 4;
        const float4* m4 = (const float4*)mean;
        float4* o4 = (float4*)out;
        for (int i = (blockIdx.x - nsel) * 256 + t; i < N4; i += 2048 * 256) {
            int bh = i >> 15, d4 = i & 15;
            o4[i] = m4[bh * 16 + d4];
        }
        return;
    }
    const int bh = blockIdx.x / NCC, kc = blockIdx.x % NCC;
    const int b = bh >> 3, h = bh & 7;
    const int k0 = kc * CC;
    // stage K^T and Q together, single barrier
    for (int i = t; i < CC * 16; i += 256) {
        int kk = i >> 4, d4 = i & 15;
        float4 kv = *(const float4*)&K[(((b * L + k0 + kk) * H + h) << 6) + d4 * 4];
        KV[(d4 * 4 + 0) * LDK + kk] = kv.x;
        KV[(d4 * 4 + 1) * LDK + kk] = kv.y;
        KV[(d4 * 4 + 2) * LDK + kk] = kv.z;
        KV[(d4 * 4 + 3) * LDK + kk] = kv.w;
    }
    for (int i = t; i < TOP * 16; i += 256) {
        int u = i >> 4, d4 = i & 15;
        int lsel = Mtop[bh * TOP + u];                 // L2-hot broadcast load
        *(float4*)&Qs[u * 64 + d4 * 4] =
            *(const float4*)&Q[(((b * L + lsel) * H + h) << 6) + d4 * 4];
    }
    // ---- prefetch V into registers (T14): loads fly during score phase ----
    float4 vpre[VPT];
    #pragma unroll
    for (int p = 0; p < VPT; ++p) {
        int i = p * 256 + t;
        int kk = i >> 4, d4 = i & 15;
        vpre[p] = *(const float4*)&V[(((b * L + k0 + kk) * H + h) << 6) + d4 * 4];
    }
    __syncthreads();
    // scores: thread owns KPT keys (k2*KPT..) x 5 queries (ug*5..)
    const int k2 = t & 31, ug = t >> 5;
    float acc[5][KPT];
    #pragma unroll
    for (int j = 0; j < 5; ++j)
        #pragma unroll
        for (int p = 0; p < KPT; ++p) acc[j][p] = 0.f;
    #pragma unroll 4
    for (int d4 = 0; d4 < 16; ++d4) {
        float kr[4][KPT];
        #pragma unroll
        for (int rr = 0; rr < 4; ++rr)
            #pragma unroll
            for (int p = 0; p < KPT; ++p)
                kr[rr][p] = KV[(d4 * 4 + rr) * LDK + k2 * KPT + p];
        #pragma unroll
        for (int j = 0; j < 5; ++j) {
            float4 q4 = *(const float4*)&Qs[(ug * 5 + j) * 64 + d4 * 4];
            #pragma unroll
            for (int p = 0; p < KPT; ++p)
                acc[j][p] += q4.x * kr[0][p] + q4.y * kr[1][p] + q4.z * kr[2][p] + q4.w * kr[3][p];
        }
    }
    #pragma unroll
    for (int j = 0; j < 5; ++j) {
        int u = ug * 5 + j;
        float z = 0.f;
        #pragma unroll
        for (int p = 0; p < KPT; ++p) {
            float e = __expf(acc[j][p] * 0.125f - 16.0f);
            Ps[u * LDP + k2 * KPT + p] = e;
            z += e;
        }
        z += __shfl_xor(z, 1); z += __shfl_xor(z, 2); z += __shfl_xor(z, 4);
        z += __shfl_xor(z, 8); z += __shfl_xor(z, 16);
        if (k2 == 0) Zpart[(bh * TOP + u) * NCC + kc] = z;
    }
    __syncthreads();
    // write prefetched V row-major over K^T space
    #pragma unroll
    for (int p = 0; p < VPT; ++p) {
        int i = p * 256 + t;
        int kk = i >> 4, d4 = i & 15;
        *(float4*)&KV[kk * LDV + d4 * 4] = vpre[p];
    }
    __syncthreads();
    // PV: thread owns d4v (4 dims) x queries {ug2, ug2+16, ug2+32(<40)}
    const int d4v = t & 15, ug2 = t >> 4;
    float4 o0 = make_float4(0,0,0,0), o1 = make_float4(0,0,0,0), o2 = make_float4(0,0,0,0);
    #pragma unroll 4
    for (int kk = 0; kk < CC; ++kk) {
        float4 vv = *(const float4*)&KV[kk * LDV + d4v * 4];
        float e0 = Ps[ug2 * LDP + kk];
        float e1 = Ps[(ug2 + 16) * LDP + kk];
        o0.x += e0 * vv.x; o0.y += e0 * vv.y; o0.z += e0 * vv.z; o0.w += e0 * vv.w;
        o1.x += e1 * vv.x; o1.y += e1 * vv.y; o1.z += e1 * vv.z; o1.w += e1 * vv.w;
        if (ug2 < 8) {                        // wave-uniform branch
            float e2 = Ps[(ug2 + 32) * LDP + kk];
            o2.x += e2 * vv.x; o2.y += e2 * vv.y; o2.z += e2 * vv.z; o2.w += e2 * vv.w;
        }
    }
    *(float4*)&Npart[((bh * TOP + ug2) * NCC + kc) * 64 + d4v * 4] = o0;
    *(float4*)&Npart[((bh * TOP + ug2 + 16) * NCC + kc) * 64 + d4v * 4] = o1;
    if (ug2 < 8)
        *(float4*)&Npart[((bh * TOP + ug2 + 32) * NCC + kc) * 64 + d4v * 4] = o2;
}

// ================= K_D: combine partials + scatter ==================
template <int NCC>
__global__ __launch_bounds__(256) void kD(const int* __restrict__ Mtop, const float* __restrict__ Npart,
                                          const float* __restrict__ Zpart, float* __restrict__ out) {
    const int t = threadIdx.x;
    const int g = blockIdx.x * 4 + (t >> 6);   // (bh,u) flat in [0,1280)
    const int d = t & 63;
    const int bh = g / TOP;
    const int lsel = Mtop[g];
    float z = 0.f;
    #pragma unroll
    for (int c = 0; c < NCC; ++c) z += Zpart[g * NCC + c];
    float n = 0.f;
    #pragma unroll
    for (int c = 0; c < NCC; ++c) n += Npart[(g * NCC + c) * 64 + d];
    out[((bh * L + lsel) << 6) + d] = n / z;
}

// ================= tier-3 fallback (tiny ws): fused per-query attention + fill ==========
__global__ void fill_ctx(const float* __restrict__ mean, float4* __restrict__ out) {
    const int N4 = B * H * L * D / 4;
    for (int i = blockIdx.x * 256 + threadIdx.x; i < N4; i += gridDim.x * 256) {
        int bh = i >> 15, d4 = i & 15;
        out[i] = ((const float4*)mean)[bh * 16 + d4];
    }
}
__global__ void sel_attn(const float* __restrict__ Q, const float* __restrict__ K,
                         const float* __restrict__ V, const int* __restrict__ Mtop,
                         float* __restrict__ out) {
    __shared__ float qs[D];
    __shared__ float p[L];
    __shared__ float red[256];
    int blk = blockIdx.x;
    int bh = blk / TOP, u = blk - bh * TOP;
    int b = bh >> 3, h = bh & 7;
    int t = threadIdx.x;
    int lsel = Mtop[bh * TOP + u];
    if (t < 64) qs[t] = Q[(((b * L + lsel) * H + h) << 6) + t];
    __syncthreads();
    float lsum = 0.f;
    for (int kk = 0; kk < 8; ++kk) {
        int k = kk * 256 + t;
        const float4* krow = (const float4*)&K[((b * L + k) * H + h) << 6];
        const float4* q4 = (const float4*)qs;
        float acc = 0.f;
        #pragma unroll
        for (int j = 0; j < 16; ++j) {
            float4 kv = krow[j]; float4 qv = q4[j];
            acc += qv.x * kv.x + qv.y * kv.y + qv.z * kv.z + qv.w * kv.w;
        }
        float e = __expf(acc * 0.125f - 16.0f);
        p[k] = e;
        lsum += e;
    }
    red[t] = lsum; __syncthreads();
    for (int off = 128; off > 0; off >>= 1) {
        if (t < off) red[t] += red[t + off];
        __syncthreads();
    }
    float inv = 1.0f / red[0];
    __syncthreads();
    int d = t & 63, c = t >> 6;
    float acc = 0.f;
    for (int k = c * 512; k < (c + 1) * 512; ++k)
        acc += p[k] * V[(((b * L + k) * H + h) << 6) + d];
    red[t] = acc; __syncthreads();
    if (t < 128) red[t] += red[t + 128];
    __syncthreads();
    if (t < 64) out[((bh * L + lsel) << 6) + t] = (red[t] + red[t + 64]) * inv;
}

extern "C" void kernel_launch(void* const* d_in, const int* in_sizes, int n_in,
                              void* d_out, int out_size, void* d_ws, size_t ws_size,
                              hipStream_t stream) {
    const float* Q = (const float*)d_in[0];
    const float* K = (const float*)d_in[1];
    const float* V = (const float*)d_in[2];
    const int* idx = (const int*)d_in[4];
    float* out = (float*)d_out;

    // --- ws layout ---
    // phase-1 (kA/kB): M at [0, 262144)
    // phase-2 (kC/kD): Zpart at [0, 163840), Npart at [163840, +npb)  (overlays dead M)
    // persistent:      Mtop / mean / Vpart after max(Npart end, 262144)
    char* ws = (char*)d_ws;
    const size_t NPB1 = (size_t)B * H * TOP * 32 * 64 * 4;   // NCC=32: 10,485,760
    const size_t NPB2 = (size_t)B * H * TOP * 16 * 64 * 4;   // NCC=16:  5,242,880
    auto layout = [&](size_t npb, size_t& persist) {
        size_t e = 163840 + npb;
        persist = (e > 262144 ? e : 262144);
        return persist + 5120 + 8192 + 131072 + 3072;        // Mtop+mean+Vpart (+pad)
    };
    size_t p1, p2, p3;
    size_t need1 = layout(NPB1, p1);
    size_t need2 = layout(NPB2, p2);
    size_t need3 = layout(0, p3);
    int tier = (ws_size >= need1) ? 1 : (ws_size >= need2) ? 2 : (ws_size >= need3) ? 3 : 0;
    size_t persist = (tier == 1) ? p1 : (tier == 2) ? p2 : p3;

    float* M     = (float*)ws;
    float* Zpart = (float*)ws;
    float* Npart = (float*)(ws + 163840);
    int*   Mtop  = (int*)(ws + persist);
    float* mean  = (float*)(ws + persist + 5120);
    float* Vpart = (float*)(ws + persist + 5120 + 8192);

    kA<<<NMB + 512, 256, 0, stream>>>(Q, K, V, idx, M, Vpart);
    kB<<<40, 256, 0, stream>>>(M, Vpart, Mtop, mean);
    if (tier == 1) {
        kC<64><<<B * H * 32 + 2048, 256, 0, stream>>>(Q, K, V, Mtop, mean, Npart, Zpart, out);
        kD<32><<<320, 256, 0, stream>>>(Mtop, Npart, Zpart, out);
    } else if (tier == 2) {
        kC<128><<<B * H * 16 + 2048, 256, 0, stream>>>(Q, K, V, Mtop, mean, Npart, Zpart, out);
        kD<16><<<320, 256, 0, stream>>>(Mtop, Npart, Zpart, out);
    } else {
        fill_ctx<<<2048, 256, 0, stream>>>(mean, (float4*)out);
        sel_attn<<<B * H * TOP, 256, 0, stream>>>(Q, K, V, Mtop, out);
    }
}